// Round 7
// baseline (123.533 us; speedup 1.0000x reference)
//
#include <hip/hip_runtime.h>
#include <hip/hip_bf16.h>

#define B_ 16
#define U_ 64
#define T_ 128
#define H_ 4
#define E_ 128
#define HID_ 256

typedef _Float16 half_t;
typedef _Float16 h2 __attribute__((ext_vector_type(2)));
typedef _Float16 f16x8 __attribute__((ext_vector_type(8)));
typedef float f32x4 __attribute__((ext_vector_type(4)));

__device__ __forceinline__ h2 u2h(unsigned u){ h2 r; __builtin_memcpy(&r, &u, 4); return r; }

#define PITCH 136   // halves; activation/weight LDS pitch (16B-aligned frags)
#define PITCH0 40   // W0 buffer (K=32)
#define KPITCH 33   // uint4 per K-row in logits LDS: conflict-free per-lane b128

// Transpose-convert: src fp32 (k-major, row len SRCN) -> dst fp16 Wt[n][k].
template<int KC, int SRCN>
__device__ __forceinline__ void stageW(const float* __restrict__ src,
    half_t* __restrict__ dst, int n, int kc0, int pitch)
{
  #pragma unroll
  for (int f=0; f<KC; f++){
    const int kc = kc0 + f;
    float v[8];
    #pragma unroll
    for (int j=0;j<8;j++) v[j] = src[(kc*8+j)*SRCN + n];
    union{ half_t h[8]; uint4 u; } p;
    #pragma unroll
    for (int j=0;j<8;j++) p.h[j] = (half_t)v[j];
    *(uint4*)(dst + n*pitch + kc*8) = p.u;
  }
}

// D row (quad*4+reg) = 4 consecutive OUT features; b64 epilogue.
template<int KTILES, int NTILES, int WPITCH, bool RELU>
__device__ __forceinline__ void layer_mfma(const half_t* __restrict__ in,
    const half_t* __restrict__ W, const float* __restrict__ bias,
    half_t* __restrict__ out, int m0, int quad, int l16)
{
  f16x8 bfrag[KTILES];
  const half_t* ip = in + (m0+l16)*PITCH + quad*8;
  #pragma unroll
  for (int kk=0;kk<KTILES;kk++) bfrag[kk] = *(const f16x8*)(ip + kk*32);
  #pragma unroll
  for (int nt=0; nt<NTILES; nt++){
    f32x4 acc = {0.f,0.f,0.f,0.f};
    const half_t* wp = W + (nt*16+l16)*WPITCH + quad*8;
    #pragma unroll
    for (int kk=0;kk<KTILES;kk++){
      f16x8 a = *(const f16x8*)(wp + kk*32);
      acc = __builtin_amdgcn_mfma_f32_16x16x32_f16(a, bfrag[kk], acc, 0, 0, 0);
    }
    const int n0 = nt*16 + quad*4;
    const float4 bv = *(const float4*)(bias + n0);
    float bvr[4] = {bv.x, bv.y, bv.z, bv.w};
    union { half_t h[4]; uint2 u; } pv;
    #pragma unroll
    for (int r=0;r<4;r++){
      float x = acc[r] + bvr[r];
      if (RELU) x = fmaxf(x, 0.f);
      pv.h[r] = (half_t)x;
    }
    *(uint2*)(out + (m0+l16)*PITCH + n0) = pv.u;
  }
}

// ---------------- fused encoder (identical to round 6) ----------------
// grid 49: blk 0..15 uav rows (writes base[b,h,u,:] fp16 = ue+qh+fb1),
// 16..47 task rows (writes Kg fp16), 48 = fw2 -> fp16 w2h.
__global__ __launch_bounds__(256) void enc_mfma(
  const float* __restrict__ uav, const float* __restrict__ task,
  const float* __restrict__ uw0, const float* __restrict__ ub0,
  const float* __restrict__ uw1, const float* __restrict__ ub1,
  const float* __restrict__ uw2, const float* __restrict__ ub2,
  const float* __restrict__ tw0, const float* __restrict__ tb0,
  const float* __restrict__ tw1, const float* __restrict__ tb1,
  const float* __restrict__ tw2, const float* __restrict__ tb2,
  const float* __restrict__ headq, const float* __restrict__ fw1,
  const float* __restrict__ fb1, const float* __restrict__ fw2,
  half_t* __restrict__ baseg, half_t* __restrict__ Kg, half_t* __restrict__ w2h)
{
  __shared__ half_t W0b[128*PITCH0];
  __shared__ half_t Wb[256*PITCH];
  __shared__ half_t actA[64*PITCH];
  __shared__ half_t actB[64*PITCH];
  __shared__ float  qf[4][256];
  const int tid = threadIdx.x;

  if (blockIdx.x == 48) { w2h[tid] = (half_t)fw2[tid]; return; }

  const int lane = tid&63, wv = tid>>6;
  const int quad = lane>>4, l16 = lane&15;
  const int m0 = wv*16;
  const bool isU = blockIdx.x < 16;
  const int rows0 = (isU ? blockIdx.x : blockIdx.x - 16) * 64;
  const float* Xsrc = (isU ? uav : task) + rows0*32;
  const float* W0 = isU ? uw0 : tw0;
  const float* W1 = isU ? uw1 : tw1;
  const float* W2 = isU ? uw2 : tw2;
  const float* W3 = fw1 + (isU ? 0 : 128*HID_);
  const float* bias0 = isU ? ub0 : tb0;
  const float* bias1 = isU ? ub1 : tb1;
  const float* bias2 = isU ? ub2 : tb2;

  const int tn = tid & 127, th = tid >> 7;

  {
    const int r = tid>>2, q = tid&3;
    const float4 v0 = *(const float4*)(Xsrc + r*32 + q*8);
    const float4 v1 = *(const float4*)(Xsrc + r*32 + q*8 + 4);
    union{ half_t h[8]; uint4 u; } p;
    p.h[0]=(half_t)v0.x; p.h[1]=(half_t)v0.y; p.h[2]=(half_t)v0.z; p.h[3]=(half_t)v0.w;
    p.h[4]=(half_t)v1.x; p.h[5]=(half_t)v1.y; p.h[6]=(half_t)v1.z; p.h[7]=(half_t)v1.w;
    *(uint4*)(actA + r*PITCH + q*8) = p.u;
  }
  stageW<2,128>(W0, W0b, tn, th*2, PITCH0);
  stageW<8,128>(W1, Wb,             tn, th*8, PITCH);
  stageW<8,128>(W2, Wb + 128*PITCH, tn, th*8, PITCH);

  if (isU){
    const int n = tid;
    float fb = fb1[n];
    float q0=fb, q1=fb, q2=fb, q3=fb;
    #pragma unroll 8
    for (int e=0;e<128;e++){
      float w = fw1[e*256 + n];
      q0 = fmaf(headq[      e], w, q0);
      q1 = fmaf(headq[128 + e], w, q1);
      q2 = fmaf(headq[256 + e], w, q2);
      q3 = fmaf(headq[384 + e], w, q3);
    }
    qf[0][n]=q0; qf[1][n]=q1; qf[2][n]=q2; qf[3][n]=q3;
  }
  __syncthreads();

  layer_mfma<1,8,PITCH0,true >(actA, W0b,          bias0, actB, m0, quad, l16);
  layer_mfma<4,8,PITCH, true >(actB, Wb,           bias1, actA, m0, quad, l16);
  __syncthreads();
  stageW<8,256>(W3, Wb, tn, th*8, PITCH);
  layer_mfma<4,8,PITCH, false>(actA, Wb+128*PITCH, bias2, actB, m0, quad, l16);
  __syncthreads();
  stageW<8,256>(W3, Wb, 128 + tn, th*8, PITCH);
  __syncthreads();

  {
    f16x8 bfrag[4];
    const half_t* ip = actB + (m0+l16)*PITCH + quad*8;
    #pragma unroll
    for (int kk=0;kk<4;kk++) bfrag[kk] = *(const f16x8*)(ip + kk*32);
    const int urow = m0 + l16;
    const int grow = rows0 + urow;
    #pragma unroll
    for (int nt=0; nt<16; nt++){
      f32x4 acc = {0.f,0.f,0.f,0.f};
      const half_t* wp = Wb + (nt*16+l16)*PITCH + quad*8;
      #pragma unroll
      for (int kk=0;kk<4;kk++){
        f16x8 a = *(const f16x8*)(wp + kk*32);
        acc = __builtin_amdgcn_mfma_f32_16x16x32_f16(a, bfrag[kk], acc, 0, 0, 0);
      }
      const int n0 = nt*16 + quad*4;
      if (isU){
        const int b = blockIdx.x;
        #pragma unroll
        for (int h=0;h<4;h++){
          const float4 qv = *(const float4*)(&qf[h][n0]);
          union { half_t hh[4]; uint2 u; } pv;
          pv.hh[0]=(half_t)(acc[0]+qv.x); pv.hh[1]=(half_t)(acc[1]+qv.y);
          pv.hh[2]=(half_t)(acc[2]+qv.z); pv.hh[3]=(half_t)(acc[3]+qv.w);
          *(uint2*)(baseg + ((size_t)((b*H_ + h)*U_ + urow))*HID_ + n0) = pv.u;
        }
      } else {
        union { half_t hh[4]; uint2 u; } pv;
        pv.hh[0]=(half_t)acc[0]; pv.hh[1]=(half_t)acc[1];
        pv.hh[2]=(half_t)acc[2]; pv.hh[3]=(half_t)acc[3];
        *(uint2*)(Kg + (size_t)grow*HID_ + n0) = pv.u;
      }
    }
  }
}

// ---------------- logits kernel ----------------
// Block = (8 u, h, b), 256 thr. LDS holds ONLY K. base/w2 read as VECTOR
// global loads (addresses formally divergent -> global_load_dwordx4; all
// lanes same address -> single L1 broadcast transaction, vmcnt pipe —
// independent of the ds_read kv stream). NO readfirstlane (round 6's s_load
// path serialized lgkmcnt with ds_read).
__global__ __launch_bounds__(256) void logits_kernel(
  const half_t* __restrict__ baseg, const half_t* __restrict__ Kg,
  const half_t* __restrict__ w2h, const float* __restrict__ fb2,
  float* __restrict__ out)
{
  __shared__ uint4 Kl[128*KPITCH];   // 67584 B

  const int tid = threadIdx.x;
  const int b = blockIdx.z, h = blockIdx.y;
  const int u0 = blockIdx.x * 8;

  const uint4* Kgp = (const uint4*)(Kg + (size_t)b*T_*HID_);
  #pragma unroll
  for (int i = tid; i < 128*32; i += 256){
    const int t = i >> 5, cc = i & 31;
    Kl[t*KPITCH + cc] = Kgp[i];
  }
  __syncthreads();

  const int wv = tid >> 6;             // left divergent on purpose
  const int lane = tid & 63;
  const int r0 = (wv & 1) * 4;
  const int t  = (wv >> 1) * 64 + lane;
  const uint4* myrow = Kl + t*KPITCH;
  const uint4* bp = (const uint4*)(baseg + ((size_t)((b*H_ + h)*U_ + u0 + r0))*HID_);
  const uint4* wp = (const uint4*)w2h;
  const float fb2f = fb2[0];
  const h2 hz = (h2)((_Float16)0);

  float acc[4] = {0.f,0.f,0.f,0.f};
  #pragma unroll 4
  for (int c=0; c<32; c++){
    const uint4 kv = myrow[c];          // per-lane LDS b128, conflict-free
    const uint4 w4 = wp[c];             // global broadcast (L1)
    #pragma unroll
    for (int r=0; r<4; r++){
      const uint4 p = bp[r*32 + c];     // global broadcast (L1)
      h2 x;
      x = __builtin_elementwise_max(u2h(p.x)+u2h(kv.x), hz);
      acc[r] = __builtin_amdgcn_fdot2(x, u2h(w4.x), acc[r], false);
      x = __builtin_elementwise_max(u2h(p.y)+u2h(kv.y), hz);
      acc[r] = __builtin_amdgcn_fdot2(x, u2h(w4.y), acc[r], false);
      x = __builtin_elementwise_max(u2h(p.z)+u2h(kv.z), hz);
      acc[r] = __builtin_amdgcn_fdot2(x, u2h(w4.z), acc[r], false);
      x = __builtin_elementwise_max(u2h(p.w)+u2h(kv.w), hz);
      acc[r] = __builtin_amdgcn_fdot2(x, u2h(w4.w), acc[r], false);
    }
  }
  #pragma unroll
  for (int r=0; r<4; r++)
    out[((b*H_ + h)*U_ + (u0 + r0 + r))*T_ + t] = acc[r] + fb2f;
}

extern "C" void kernel_launch(void* const* d_in, const int* in_sizes, int n_in,
                              void* d_out, int out_size, void* d_ws, size_t ws_size,
                              hipStream_t stream)
{
  const float* uav  = (const float*)d_in[0];
  const float* task = (const float*)d_in[1];
  const float* uw0=(const float*)d_in[2];  const float* ub0=(const float*)d_in[3];
  const float* uw1=(const float*)d_in[4];  const float* ub1=(const float*)d_in[5];
  const float* uw2=(const float*)d_in[6];  const float* ub2=(const float*)d_in[7];
  const float* tw0=(const float*)d_in[8];  const float* tb0=(const float*)d_in[9];
  const float* tw1=(const float*)d_in[10]; const float* tb1=(const float*)d_in[11];
  const float* tw2=(const float*)d_in[12]; const float* tb2=(const float*)d_in[13];
  const float* headq=(const float*)d_in[14];
  const float* fw1=(const float*)d_in[15];
  const float* fb1=(const float*)d_in[16];
  const float* fw2=(const float*)d_in[17];
  const float* fb2=(const float*)d_in[18];

  half_t* baseg = (half_t*)d_ws;                    // B*H*U*256 halves (2 MB)
  half_t* Kg    = baseg + (size_t)B_*H_*U_*HID_;    // B*T*256 halves (1 MB)
  half_t* w2h   = Kg + (size_t)B_*T_*HID_;          // 256 halves

  float* out = (float*)d_out;

  hipLaunchKernelGGL(enc_mfma, dim3(49), dim3(256), 0, stream,
      uav, task, uw0, ub0, uw1, ub1, uw2, ub2,
      tw0, tb0, tw1, tb1, tw2, tb2, headq, fw1, fb1, fw2,
      baseg, Kg, w2h);
  hipLaunchKernelGGL(logits_kernel, dim3(U_/8, H_, B_), dim3(256), 0, stream,
      baseg, Kg, w2h, fb2, out);
}

// Round 8
// 111.544 us; speedup vs baseline: 1.1075x; 1.1075x over previous
//
#include <hip/hip_runtime.h>
#include <hip/hip_bf16.h>

#define B_ 16
#define U_ 64
#define T_ 128
#define H_ 4
#define E_ 128
#define HID_ 256

typedef _Float16 half_t;
typedef _Float16 h2 __attribute__((ext_vector_type(2)));
typedef _Float16 f16x8 __attribute__((ext_vector_type(8)));
typedef float f32x4 __attribute__((ext_vector_type(4)));

__device__ __forceinline__ h2 u2h(unsigned u){ h2 r; __builtin_memcpy(&r, &u, 4); return r; }
__device__ __forceinline__ unsigned pkh(float a, float b){
  h2 r; r.x = (_Float16)a; r.y = (_Float16)b;
  unsigned u; __builtin_memcpy(&u, &r, 4); return u;
}

#define PITCH 136   // halves; 272 B row stride -> b128 frags 16B-aligned, conflict-free
#define PITCH0 40   // W0 buffer (K=32)

// Transpose-convert: src fp32 (k-major, row len SRCN) -> dst fp16 Wt[n][k].
template<int KC, int SRCN>
__device__ __forceinline__ void stageW(const float* __restrict__ src,
    half_t* __restrict__ dst, int n, int kc0, int pitch)
{
  #pragma unroll
  for (int f=0; f<KC; f++){
    const int kc = kc0 + f;
    float v[8];
    #pragma unroll
    for (int j=0;j<8;j++) v[j] = src[(kc*8+j)*SRCN + n];
    union{ half_t h[8]; uint4 u; } p;
    #pragma unroll
    for (int j=0;j<8;j++) p.h[j] = (half_t)v[j];
    *(uint4*)(dst + n*pitch + kc*8) = p.u;
  }
}

// n-split layer: wave handles row tile m0 and NT n-tiles starting at nt0.
// D row (quad*4+reg) = 4 consecutive OUT features; b64 epilogue.
template<int KTILES, int NT, int WPITCH, bool RELU>
__device__ __forceinline__ void layer_ns(const half_t* __restrict__ in,
    const half_t* __restrict__ W, const float* __restrict__ bias,
    half_t* __restrict__ out, int m0, int nt0, int quad, int l16)
{
  f16x8 bfrag[KTILES];
  const half_t* ip = in + (m0+l16)*PITCH + quad*8;
  #pragma unroll
  for (int kk=0;kk<KTILES;kk++) bfrag[kk] = *(const f16x8*)(ip + kk*32);
  #pragma unroll
  for (int j=0; j<NT; j++){
    const int nt = nt0 + j;
    f32x4 acc = {0.f,0.f,0.f,0.f};
    const half_t* wp = W + (nt*16+l16)*WPITCH + quad*8;
    #pragma unroll
    for (int kk=0;kk<KTILES;kk++){
      f16x8 a = *(const f16x8*)(wp + kk*32);
      acc = __builtin_amdgcn_mfma_f32_16x16x32_f16(a, bfrag[kk], acc, 0, 0, 0);
    }
    const int n0 = nt*16 + quad*4;
    const float4 bv = *(const float4*)(bias + n0);
    float bvr[4] = {bv.x, bv.y, bv.z, bv.w};
    union { half_t h[4]; uint2 u; } pv;
    #pragma unroll
    for (int r=0;r<4;r++){
      float x = acc[r] + bvr[r];
      if (RELU) x = fmaxf(x, 0.f);
      pv.h[r] = (half_t)x;
    }
    *(uint2*)(out + (m0+l16)*PITCH + n0) = pv.u;
  }
}

// ---------------- fused encoder: 32 rows/block, n-split waves ----------------
// grid 97: blk 0..31 uav rows (-> ueW fp32), 32..95 task rows (-> Kg fp16),
// 96 = QhW (= head_q @ fw1[:E]).  Wave = (row-tile tr, n-half nh).
__global__ __launch_bounds__(256) void enc_mfma(
  const float* __restrict__ uav, const float* __restrict__ task,
  const float* __restrict__ uw0, const float* __restrict__ ub0,
  const float* __restrict__ uw1, const float* __restrict__ ub1,
  const float* __restrict__ uw2, const float* __restrict__ ub2,
  const float* __restrict__ tw0, const float* __restrict__ tb0,
  const float* __restrict__ tw1, const float* __restrict__ tb1,
  const float* __restrict__ tw2, const float* __restrict__ tb2,
  const float* __restrict__ headq, const float* __restrict__ fw1,
  float* __restrict__ ueW, half_t* __restrict__ Kg, float* __restrict__ QhW)
{
  __shared__ half_t W0b[128*PITCH0];   // 10240 B
  __shared__ half_t Wb[256*PITCH];     // 69632 B (lo = rows 0..127, hi = 128..255)
  __shared__ half_t actA[32*PITCH];    // 8704 B
  __shared__ half_t actB[32*PITCH];    // 8704 B
  const int tid = threadIdx.x;

  if (blockIdx.x == 96) {              // QhW: 4x256 = head_q @ fw1[:128]
    const int n = tid;
    float acc[4] = {0.f,0.f,0.f,0.f};
    for (int e=0;e<128;e++){
      float w = fw1[e*256 + n];        // coalesced across tid
      #pragma unroll
      for (int h=0;h<4;h++) acc[h] = fmaf(headq[h*128+e], w, acc[h]);
    }
    #pragma unroll
    for (int h=0;h<4;h++) QhW[h*256+n] = acc[h];
    return;
  }

  const int lane = tid&63, wv = tid>>6;
  const int quad = lane>>4, l16 = lane&15;
  const int tr = wv & 1, nh = wv >> 1;
  const int m0 = tr*16;
  const bool isU = blockIdx.x < 32;
  const int rows0 = (isU ? blockIdx.x : blockIdx.x - 32) * 32;
  const float* Xsrc = (isU ? uav : task) + rows0*32;
  const float* W0 = isU ? uw0 : tw0;
  const float* W1 = isU ? uw1 : tw1;
  const float* W2 = isU ? uw2 : tw2;
  const float* W3 = fw1 + (isU ? 0 : 128*HID_);
  const float* bias0 = isU ? ub0 : tb0;
  const float* bias1 = isU ? ub1 : tb1;
  const float* bias2 = isU ? ub2 : tb2;

  const int tn = tid & 127, th = tid >> 7;

  // ---- stage X (32 rows x 32 k, fp32 -> fp16) + W0 + W1 + W2 ----
  if (tid < 128){
    const int r = tid>>2, q = tid&3;
    const float4 v0 = *(const float4*)(Xsrc + r*32 + q*8);
    const float4 v1 = *(const float4*)(Xsrc + r*32 + q*8 + 4);
    union{ half_t h[8]; uint4 u; } p;
    p.h[0]=(half_t)v0.x; p.h[1]=(half_t)v0.y; p.h[2]=(half_t)v0.z; p.h[3]=(half_t)v0.w;
    p.h[4]=(half_t)v1.x; p.h[5]=(half_t)v1.y; p.h[6]=(half_t)v1.z; p.h[7]=(half_t)v1.w;
    *(uint4*)(actA + r*PITCH + q*8) = p.u;
  }
  stageW<2,128>(W0, W0b, tn, th*2, PITCH0);
  stageW<8,128>(W1, Wb,             tn, th*8, PITCH);
  stageW<8,128>(W2, Wb + 128*PITCH, tn, th*8, PITCH);
  __syncthreads();

  layer_ns<1,4,PITCH0,true >(actA, W0b,          bias0, actB, m0, nh*4, quad, l16);
  __syncthreads();                       // n-split: next layer reads all columns
  layer_ns<4,4,PITCH, true >(actB, Wb,           bias1, actA, m0, nh*4, quad, l16);
  __syncthreads();                       // Wb lo (W1) free; actA complete
  stageW<8,256>(W3, Wb, tn, th*8, PITCH);              // W3 rows 0..127 -> Wb lo
  layer_ns<4,4,PITCH, false>(actA, Wb+128*PITCH, bias2, actB, m0, nh*4, quad, l16);
  __syncthreads();                       // Wb hi (W2) free; actB complete
  stageW<8,256>(W3, Wb, 128 + tn, th*8, PITCH);        // W3 rows 128..255 -> Wb hi
  __syncthreads();

  // L3: K=128 -> N=256 (wave: 8 nt starting nh*8), no bias/relu, to global
  {
    f16x8 bfrag[4];
    const half_t* ip = actB + (m0+l16)*PITCH + quad*8;
    #pragma unroll
    for (int kk=0;kk<4;kk++) bfrag[kk] = *(const f16x8*)(ip + kk*32);
    const int grow = rows0 + m0 + l16;
    #pragma unroll
    for (int j=0; j<8; j++){
      const int nt = nh*8 + j;
      f32x4 acc = {0.f,0.f,0.f,0.f};
      const half_t* wp = Wb + (nt*16+l16)*PITCH + quad*8;
      #pragma unroll
      for (int kk=0;kk<4;kk++){
        f16x8 a = *(const f16x8*)(wp + kk*32);
        acc = __builtin_amdgcn_mfma_f32_16x16x32_f16(a, bfrag[kk], acc, 0, 0, 0);
      }
      const int n0 = nt*16 + quad*4;
      if (isU){
        *(float4*)(ueW + grow*256 + n0) = make_float4(acc[0],acc[1],acc[2],acc[3]);
      } else {
        union { half_t hh[4]; uint2 u; } pv;
        pv.hh[0]=(half_t)acc[0]; pv.hh[1]=(half_t)acc[1];
        pv.hh[2]=(half_t)acc[2]; pv.hh[3]=(half_t)acc[3];
        *(uint2*)(Kg + (size_t)grow*HID_ + n0) = pv.u;
      }
    }
  }
}

// ---------------- logits kernel (round-5 version, verbatim) ----------------
// Block = (8 u, h, b), 256 thr. All 128 t staged once (64 KB, rotation
// swizzle). Wave = (row-quad, t-half): 4 u-rows x 64 t. base/w2 as LDS
// broadcasts (cheap); single barrier.
#define UTILE 8

__global__ __launch_bounds__(256) void logits_kernel(
  const float* __restrict__ ueW, const float* __restrict__ QhW,
  const half_t* __restrict__ Kg,
  const float* __restrict__ fb1, const float* __restrict__ fw2,
  const float* __restrict__ fb2, float* __restrict__ out)
{
  __shared__ uint4 Kl4[128*32];      // 64 KB: [t][(c+t)&31]
  __shared__ uint4 baseb[UTILE][32]; // fp16 pairs of ueW+QhW+fb1
  __shared__ uint4 w2b[32];          // fp16 pairs of fw2

  const int tid = threadIdx.x;
  const int b = blockIdx.z, h = blockIdx.y;
  const int u0 = blockIdx.x * UTILE;

  {
    const int u = tid >> 5;
    const int c = tid & 31;
    const float4* ue4 = (const float4*)(ueW + (b*U_ + u0 + u)*HID_);
    const float4* q4  = (const float4*)(QhW + h*HID_);
    const float4* f4  = (const float4*)fb1;
    float4 a0 = ue4[2*c],   a1 = ue4[2*c+1];
    float4 b0 = q4[2*c],    b1 = q4[2*c+1];
    float4 c0 = f4[2*c],    c1 = f4[2*c+1];
    uint4 pv;
    pv.x = pkh(a0.x+b0.x+c0.x, a0.y+b0.y+c0.y);
    pv.y = pkh(a0.z+b0.z+c0.z, a0.w+b0.w+c0.w);
    pv.z = pkh(a1.x+b1.x+c1.x, a1.y+b1.y+c1.y);
    pv.w = pkh(a1.z+b1.z+c1.z, a1.w+b1.w+c1.w);
    baseb[u][c] = pv;
    if (tid < 32) {
      const float4* w4 = (const float4*)fw2;
      float4 w0 = w4[2*tid], w1 = w4[2*tid+1];
      uint4 wv4;
      wv4.x = pkh(w0.x, w0.y); wv4.y = pkh(w0.z, w0.w);
      wv4.z = pkh(w1.x, w1.y); wv4.w = pkh(w1.z, w1.w);
      w2b[tid] = wv4;
    }
  }
  const uint4* Kgp = (const uint4*)(Kg + (size_t)b*T_*HID_);
  #pragma unroll
  for (int i = tid; i < 128*32; i += 256){
    const int t = i >> 5, c = i & 31;
    Kl4[t*32 + ((c + t)&31)] = Kgp[t*32 + c];
  }
  __syncthreads();

  const int wv = tid >> 6, lane = tid & 63;
  const int r0 = (wv & 1) * 4;
  const int t  = (wv >> 1) * 64 + lane;
  const float fb2f = fb2[0];
  const uint4* myrow = Kl4 + t*32;
  const h2 hz = (h2)((_Float16)0);

  float acc[4] = {0.f,0.f,0.f,0.f};
  #pragma unroll
  for (int c=0; c<32; c++){
    const uint4 kv = myrow[(c + t)&31];
    const uint4 w4 = w2b[c];
    #pragma unroll
    for (int r=0; r<4; r++){
      const uint4 p = baseb[r0+r][c];
      h2 x;
      x = __builtin_elementwise_max(u2h(p.x)+u2h(kv.x), hz);
      acc[r] = __builtin_amdgcn_fdot2(x, u2h(w4.x), acc[r], false);
      x = __builtin_elementwise_max(u2h(p.y)+u2h(kv.y), hz);
      acc[r] = __builtin_amdgcn_fdot2(x, u2h(w4.y), acc[r], false);
      x = __builtin_elementwise_max(u2h(p.z)+u2h(kv.z), hz);
      acc[r] = __builtin_amdgcn_fdot2(x, u2h(w4.z), acc[r], false);
      x = __builtin_elementwise_max(u2h(p.w)+u2h(kv.w), hz);
      acc[r] = __builtin_amdgcn_fdot2(x, u2h(w4.w), acc[r], false);
    }
  }
  #pragma unroll
  for (int r=0; r<4; r++)
    out[((b*H_ + h)*U_ + (u0 + r0 + r))*T_ + t] = acc[r] + fb2f;
}

extern "C" void kernel_launch(void* const* d_in, const int* in_sizes, int n_in,
                              void* d_out, int out_size, void* d_ws, size_t ws_size,
                              hipStream_t stream)
{
  const float* uav  = (const float*)d_in[0];
  const float* task = (const float*)d_in[1];
  const float* uw0=(const float*)d_in[2];  const float* ub0=(const float*)d_in[3];
  const float* uw1=(const float*)d_in[4];  const float* ub1=(const float*)d_in[5];
  const float* uw2=(const float*)d_in[6];  const float* ub2=(const float*)d_in[7];
  const float* tw0=(const float*)d_in[8];  const float* tb0=(const float*)d_in[9];
  const float* tw1=(const float*)d_in[10]; const float* tb1=(const float*)d_in[11];
  const float* tw2=(const float*)d_in[12]; const float* tb2=(const float*)d_in[13];
  const float* headq=(const float*)d_in[14];
  const float* fw1=(const float*)d_in[15];
  const float* fb1=(const float*)d_in[16];
  const float* fw2=(const float*)d_in[17];
  const float* fb2=(const float*)d_in[18];

  float* ueW = (float*)d_ws;                 // 262144 floats (1 MB)
  float* QhW = ueW + 262144;                 // 1024 floats
  half_t* Kg = (half_t*)(QhW + 1024);        // 524288 halves (1 MB)

  float* out = (float*)d_out;

  hipLaunchKernelGGL(enc_mfma, dim3(97), dim3(256), 0, stream,
      uav, task, uw0, ub0, uw1, ub1, uw2, ub2,
      tw0, tb0, tw1, tb1, tw2, tb2, headq, fw1,
      ueW, Kg, QhW);
  hipLaunchKernelGGL(logits_kernel, dim3(U_/UTILE, H_, B_), dim3(256), 0, stream,
      ueW, QhW, Kg, fb1, fw2, fb2, out);
}